// Round 10
// baseline (600.627 us; speedup 1.0000x reference)
//
#include <hip/hip_runtime.h>
#include <float.h>
#include <math.h>

// Problem constants (fixed by the reference: N=8192, D=512, k+1=31).
#define NN 8192
#define DD 512
#define TOPK 31
#define CAPW 192          // per-row candidate cap (typical cnt ~50)
#define DELTA 1e-4f       // sound |approx-exact| bound: lo*lo + requant ~5e-5

// Strategy (R17 = R16 + 8-wave sim blocks for TLP):
//   Bit-exact value chain (absmax 0.0 since R3):
//     h = relu(f*W1)*W2 ; n = sqrtf(numpy-pairwise sum h*h) ; e = h/n
//     sim[i][j] = sequential-k fmaf chain over e_i*e_j ; stable top-31
//   Approx sim = bf16 MFMA: e = hi+lo, acc = hi*hi + lo*hi + hi*lo.
//   sim: 128x128 tile, 512 threads (8 waves, 2x4 grid, 64x32 per wave),
//   2-phase double-buffered global_load_lds (4 loads/k-step, vmcnt(4)
//   counted wait), bijective XCD swizzle. Same 64KB LDS -> 2 blocks/CU but
//   16 waves/CU (was 8): doubles latency hiding, acc drops to 8 f32x4/wave.
//   Round-up bf16 scratch in the SECOND 16KB of each output f32 row + TM.
//   collect (1 wave/row): tile-skip scan (tmax < Tc -> skip loads; sound),
//   zero BOTH row halves during scan, exact fmaf chains re-rank to LDS,
//   scatter 31 values after the barrier. cleanup rewrites flagged rows.

typedef __attribute__((ext_vector_type(8))) short short8;
typedef __attribute__((ext_vector_type(4))) float f32x4;

__device__ __forceinline__ float h_elem(const float* __restrict__ f,
                                        const float* __restrict__ W1,
                                        const float* __restrict__ W2, int k) {
  float x = f[k] * W1[k];
  x = fmaxf(x, 0.0f);
  return x * W2[k];
}

__device__ __forceinline__ unsigned short f2bf_rne(float x) {
  unsigned u = __float_as_uint(x);
  unsigned r = (u >> 16) & 1u;
  u += 0x7fffu + r;
  return (unsigned short)(u >> 16);
}
// Round toward +inf: guarantees bf16(x) >= x. (pos: ceil; neg: trunc->up)
__device__ __forceinline__ unsigned short f2bf_ru(float x) {
  unsigned u = __float_as_uint(x);
  if (!(u >> 31)) u += 0xffffu;
  return (unsigned short)(u >> 16);
}
__device__ __forceinline__ float bf2f(unsigned short h) {
  return __uint_as_float(((unsigned)h) << 16);
}
__device__ __forceinline__ unsigned ordmap(float x) {
  unsigned u = __float_as_uint(x);
  return (u & 0x80000000u) ? ~u : (u | 0x80000000u);
}

// async global->LDS, 16B per lane (dest = wave-uniform base + lane*16)
__device__ __forceinline__ void gl16(const void* g, void* l) {
  __builtin_amdgcn_global_load_lds(
      (const __attribute__((address_space(1))) void*)g,
      (__attribute__((address_space(3))) void*)l, 16, 0, 0);
}

// bf16 scratch image of sim row i: second half of output row i's 32KB span.
__device__ __forceinline__ unsigned short* bfrow(float* C, int row) {
  return (unsigned short*)C + (size_t)row * (2 * NN) + NN;
}

// ---------------------------------------------------------------------------
// Kernel A: fused norm (numpy pairwise association, bit-exact) + e = h/n,
// bf16 hi/lo split (RNE), flag zeroing. One wave per row.
// ---------------------------------------------------------------------------
__global__ __launch_bounds__(256) void emb_kernel(
    const float* __restrict__ f, const float* __restrict__ W1,
    const float* __restrict__ W2, float* __restrict__ e32,
    unsigned short* __restrict__ Ehi, unsigned short* __restrict__ Elo,
    int* __restrict__ flags) {
  const int lane = threadIdx.x & 63;
  const int row = blockIdx.x * 4 + (threadIdx.x >> 6);
  const float* fr = f + (size_t)row * DD;
  const int b = lane >> 4, L = lane & 15;
  if (lane == 0) flags[row] = 0;

  float s[8];
#pragma unroll
  for (int j = 0; j < 8; ++j) {
    float h = h_elem(fr, W1, W2, b * 128 + 16 * j + L);
    s[j] = h * h;
  }
  float v = ((s[0] + s[1]) + (s[2] + s[3])) + ((s[4] + s[5]) + (s[6] + s[7]));
  float t = v + __shfl_xor(v, 8);
  t = t + __shfl_xor(t, 4);
  t = t + __shfl_xor(t, 2);
  float nb = t + __shfl_xor(t, 1);
  float x = nb + __shfl_xor(nb, 16);
  float norm2 = x + __shfl_xor(x, 32);
  const float n = fmaxf(sqrtf(norm2), 1e-12f);

  float* er = e32 + (size_t)row * DD;
  unsigned short* hr = Ehi + (size_t)row * DD;
  unsigned short* lr = Elo + (size_t)row * DD;
#pragma unroll
  for (int m = 0; m < 8; ++m) {
    int k = m * 64 + lane;
    float e = h_elem(fr, W1, W2, k) / n;
    er[k] = e;
    unsigned short hb = f2bf_rne(e);
    hr[k] = hb;
    lr[k] = f2bf_rne(e - bf2f(hb));
  }
}

// ---------------------------------------------------------------------------
// Kernel B: merged 3-term bf16 MFMA sim, upper-triangle 128x128 tiles,
// 512 threads = 8 waves (2 row-bands x 4 col-bands; 64x32 output per wave).
// Counted-vmcnt K-loop (BK=32): STAGE(next: 4 x full-tile gl16) ->
// s_waitcnt vmcnt(4) -> s_barrier -> frag reads + 24 MFMAs/wave -> s_barrier.
// Linear LDS tiles AH|AL|BH|BL (8KB each) x 2 buffers (64KB).
// Epilogue: round-up bf16 tile write + per-row tile-max TM + (bx>by)
// transposed mirror tile via LDS strips + transposed TM.
// ---------------------------------------------------------------------------
#define OFS_AL 4096   // short offsets into a buffer
#define OFS_BH 8192
#define OFS_BL 12288

#define STAGE(BUF, KK)                        \
  do {                                        \
    char* Ld = L0 + ((BUF) << 15);            \
    gl16(Ehi + rA + (KK), Ld);                \
    gl16(Elo + rA + (KK), Ld + 8192);         \
    gl16(Ehi + rB + (KK), Ld + 16384);        \
    gl16(Elo + rB + (KK), Ld + 24576);        \
  } while (0)

__global__ __launch_bounds__(512) void sim_mfma(
    const unsigned short* __restrict__ Ehi,
    const unsigned short* __restrict__ Elo, float* __restrict__ C,
    float* __restrict__ TM) {
  // bijective XCD swizzle (2080 % 8 == 0): consecutive swz within an XCD
  // share the by-band -> A-panel L2 locality on the XCD's private L2.
  int swz = (blockIdx.x & 7) * 260 + (blockIdx.x >> 3);
  // triangular decode: 2080 -> (bx, by) with bx >= by
  int rem = swz, by = 0;
  while (rem >= 64 - by) { rem -= 64 - by; ++by; }
  const int bx = by + rem;

  __shared__ __align__(16) char smem[65536];  // 2 x 32KB ping-pong; epi alias
  unsigned short* S = (unsigned short*)smem;
  char* Sc = smem;
  float(*Tt)[133] = (float(*)[133])smem;  // epilogue alias ([64][133] = 34048B)
  __shared__ float rmx[128][4];
  __shared__ float cmx[128][2];

  const int t = threadIdx.x;           // 0..511
  const int lane = t & 63, w = t >> 6; // w 0..7
  const int wr = w >> 2, wc = w & 3;   // 2 row-bands x 4 col-bands
  const int quad = lane >> 4, l16 = lane & 15;
  const int i0 = by * 128, j0 = bx * 128;

  f32x4 acc[4][2];
#pragma unroll
  for (int a = 0; a < 4; ++a)
#pragma unroll
    for (int b = 0; b < 2; ++b) acc[a][b] = (f32x4){0.f, 0.f, 0.f, 0.f};

  // staging: thread t writes LDS bytes [t*16, t*16+16) of each 8KB tensor
  // tile == row (t>>2), chunk (t&3) of a linear [128][32-short] tile.
  const size_t rA = (size_t)(i0 + (t >> 2)) * DD + (t & 3) * 8;
  const size_t rB = (size_t)(j0 + (t >> 2)) * DD + (t & 3) * 8;
  char* L0 = Sc + (w << 10);  // wave-uniform LDS base (wave w: bytes w*1024+)

  STAGE(0, 0);  // 4 loads in flight

  int cur = 0;
  for (int kk = 0; kk < DD; kk += 32) {
    if (kk + 32 < DD) {
      STAGE(cur ^ 1, kk + 32);  // +4 -> 8 in flight
      asm volatile("s_waitcnt vmcnt(4)" ::: "memory");  // cur's 4 landed
    } else {
      asm volatile("s_waitcnt vmcnt(0)" ::: "memory");  // last tile: drain
    }
    __builtin_amdgcn_s_barrier();  // every wave waited -> whole tile resident

    const unsigned short* Sb = S + (cur << 14);  // cur*16384 shorts
    short8 ah[4], al[4], bh[2];
#pragma unroll
    for (int mt = 0; mt < 4; ++mt) {
      int rr = (wr * 64 + mt * 16 + l16) * 32 + quad * 8;
      ah[mt] = *(const short8*)&Sb[rr];
      al[mt] = *(const short8*)&Sb[OFS_AL + rr];
    }
#pragma unroll
    for (int nt = 0; nt < 2; ++nt)
      bh[nt] = *(const short8*)&Sb[OFS_BH + (wc * 32 + nt * 16 + l16) * 32 + quad * 8];
#pragma unroll
    for (int mt = 0; mt < 4; ++mt)
#pragma unroll
      for (int nt = 0; nt < 2; ++nt)
        acc[mt][nt] = __builtin_amdgcn_mfma_f32_16x16x32_bf16(ah[mt], bh[nt], acc[mt][nt], 0, 0, 0);
#pragma unroll
    for (int mt = 0; mt < 4; ++mt)
#pragma unroll
      for (int nt = 0; nt < 2; ++nt)
        acc[mt][nt] = __builtin_amdgcn_mfma_f32_16x16x32_bf16(al[mt], bh[nt], acc[mt][nt], 0, 0, 0);
    short8 bl[2];
#pragma unroll
    for (int nt = 0; nt < 2; ++nt)
      bl[nt] = *(const short8*)&Sb[OFS_BL + (wc * 32 + nt * 16 + l16) * 32 + quad * 8];
#pragma unroll
    for (int mt = 0; mt < 4; ++mt)
#pragma unroll
      for (int nt = 0; nt < 2; ++nt)
        acc[mt][nt] = __builtin_amdgcn_mfma_f32_16x16x32_bf16(ah[mt], bl[nt], acc[mt][nt], 0, 0, 0);

    __builtin_amdgcn_s_barrier();  // all waves done reading cur before it's
    cur ^= 1;                      // overwritten by next iteration's STAGE
  }

  // --- normal tile write: round-up bf16 into per-row scratch ---
#pragma unroll
  for (int mt = 0; mt < 4; ++mt)
#pragma unroll
    for (int r = 0; r < 4; ++r) {
      int row = i0 + wr * 64 + mt * 16 + quad * 4 + r;
      unsigned short* Br = bfrow(C, row) + j0 + wc * 32;
#pragma unroll
      for (int nt = 0; nt < 2; ++nt) Br[nt * 16 + l16] = f2bf_ru(acc[mt][nt][r]);
    }

  // --- per-row tile-max (rows of this tile); rmx col = wc (32-col band) ---
#pragma unroll
  for (int mt = 0; mt < 4; ++mt)
#pragma unroll
    for (int r = 0; r < 4; ++r) {
      float m = fmaxf(acc[mt][0][r], acc[mt][1][r]);
      m = fmaxf(m, __shfl_xor(m, 1));
      m = fmaxf(m, __shfl_xor(m, 2));
      m = fmaxf(m, __shfl_xor(m, 4));
      m = fmaxf(m, __shfl_xor(m, 8));
      if (l16 == 0) rmx[wr * 64 + mt * 16 + quad * 4 + r][wc] = m;
    }
  // --- per-col tile-max (rows of the mirrored tile), only if off-diagonal ---
  if (bx > by) {
#pragma unroll
    for (int nt = 0; nt < 2; ++nt) {
      float c = -FLT_MAX;
#pragma unroll
      for (int mt = 0; mt < 4; ++mt)
#pragma unroll
        for (int r = 0; r < 4; ++r) c = fmaxf(c, acc[mt][nt][r]);
      c = fmaxf(c, __shfl_xor(c, 16));
      c = fmaxf(c, __shfl_xor(c, 32));
      if (quad == 0) cmx[wc * 32 + nt * 16 + l16][wr] = c;
    }
  }
  __syncthreads();
  if (t < 128)
    TM[(size_t)(i0 + t) * 64 + bx] =
        fmaxf(fmaxf(rmx[t][0], rmx[t][1]), fmaxf(rmx[t][2], rmx[t][3]));
  if (bx > by) {
    if (t < 128) TM[(size_t)(j0 + t) * 64 + by] = fmaxf(cmx[t][0], cmx[t][1]);
    // --- transposed mirror write via LDS strips (Tt aliases S), bf16-RU out ---
    for (int s = 0; s < 2; ++s) {
      __syncthreads();
      if ((wc >> 1) == s) {
#pragma unroll
        for (int mt = 0; mt < 4; ++mt)
#pragma unroll
          for (int nt = 0; nt < 2; ++nt)
#pragma unroll
            for (int r = 0; r < 4; ++r)
              Tt[(wc & 1) * 32 + nt * 16 + l16][wr * 64 + mt * 16 + quad * 4 + r] =
                  acc[mt][nt][r];
      }
      __syncthreads();
      // write out [64][128] floats = 2048 float4; 512 threads -> 4 each
#pragma unroll
      for (int q = 0; q < 4; ++q) {
        int fi = q * 512 + t;
        int rr = fi >> 5;
        int cc4 = (fi & 31) * 4;
        ushort4 v;
        v.x = f2bf_ru(Tt[rr][cc4]);
        v.y = f2bf_ru(Tt[rr][cc4 + 1]);
        v.z = f2bf_ru(Tt[rr][cc4 + 2]);
        v.w = f2bf_ru(Tt[rr][cc4 + 3]);
        *(ushort4*)(bfrow(C, j0 + s * 64 + rr) + i0 + cc4) = v;
      }
    }
  }
}

// ---------------------------------------------------------------------------
// Kernel C: collect+write. One WAVE per row (4 rows/block). T = 31st largest
// tile-max via O(64) rank-select. Single pass over the bf16-RU row scratch:
// SKIP loads for tiles with tmax < Tc (sound; output-identical), collect
// cands >= T - 2*DELTA, zero BOTH halves of the output row. Exact fmaf
// chains re-rank into LDS kidx/kval; __syncthreads (vmcnt drain: zeros
// committed); lanes 0..30 scatter the 31 final values. Overflow -> flag,
// predicated skip (zeros already written; cleanup rewrites the row).
// ---------------------------------------------------------------------------
__global__ __launch_bounds__(256) void topk_collect(
    float* __restrict__ C, const float* __restrict__ e32,
    const float* __restrict__ TM, int* __restrict__ flags) {
  const int w = threadIdx.x >> 6;
  const int lane = threadIdx.x & 63;
  const int row = blockIdx.x * 4 + w;

  __shared__ float er[4][DD];
  __shared__ int cidx[4][CAPW];
  __shared__ float cval[4][CAPW];
  __shared__ int wcnt[4];
  __shared__ int kidx[4][TOPK];
  __shared__ float kval[4][TOPK];

  {
    const float4* e4 = (const float4*)(e32 + (size_t)row * DD);
    float4* er4 = (float4*)er[w];
    er4[lane] = e4[lane];
    er4[64 + lane] = e4[64 + lane];
  }
  if (lane == 0) wcnt[w] = 0;

  // T = 31st largest of 64 tile maxima: rank-select with independent shuffles.
  const float mv = TM[(size_t)row * 64 + lane];  // preserved for tile-skip
  unsigned key = ordmap(mv);
  int rank = 0;
#pragma unroll
  for (int off = 1; off < 64; ++off) {
    int ol = (lane + off) & 63;
    unsigned ok2 = __shfl(key, ol);
    rank += (ok2 > key || (ok2 == key && ol < lane)) ? 1 : 0;
  }
  unsigned long long bmsk = __ballot(rank == TOPK - 1);
  float T = __shfl(mv, __ffsll((unsigned long long)bmsk) - 1);

  // single row pass: tile-skip scan + candidates + zero BOTH row halves
  const float Tc = T - 2.0f * DELTA;
  unsigned short* Brow = bfrow(C, row);
  const uint4* Br4 = (const uint4*)Brow;
  uint4* Bw4 = (uint4*)Brow;                      // scratch half (16KB)
  float4* Zw4 = (float4*)(C + (size_t)row * NN);  // first 16KB = 1024 float4
  const float4 z4 = make_float4(0.f, 0.f, 0.f, 0.f);
  const uint4 zu4 = {0u, 0u, 0u, 0u};
  for (int it = 0; it < NN / 512; ++it) {
    // lane's 8 columns this iteration lie in tile it*4 + (lane>>4)
    const float tmx = __shfl(mv, it * 4 + (lane >> 4));
    const bool live = (tmx >= Tc);
    uint4 v = zu4;
    if (live) v = Br4[it * 64 + lane];
    Zw4[it * 64 + lane] = z4;
    Bw4[it * 64 + lane] = zu4;
    if (live) {
      int j = (it * 64 + lane) * 8;
      unsigned wv[4] = {v.x, v.y, v.z, v.w};
#pragma unroll
      for (int c = 0; c < 4; ++c) {
        float f0 = __uint_as_float(wv[c] << 16);
        float f1 = __uint_as_float(wv[c] & 0xffff0000u);
        if (f0 >= Tc) { int p = atomicAdd(&wcnt[w], 1); if (p < CAPW) cidx[w][p] = j + 2 * c; }
        if (f1 >= Tc) { int p = atomicAdd(&wcnt[w], 1); if (p < CAPW) cidx[w][p] = j + 2 * c + 1; }
      }
    }
  }
  const int cnt = wcnt[w];
  const bool ok = (cnt <= CAPW);
  if (!ok && lane == 0) flags[row] = 1;

  // exact sequential-k fmaf chains (bit-identical to the verified chain)
  if (ok) {
    for (int c = lane; c < cnt; c += 64) {
      const float4* ej4 = (const float4*)(e32 + (size_t)cidx[w][c] * DD);
      float a = 0.f;
      for (int k4 = 0; k4 < DD / 4; ++k4) {
        float4 vv = ej4[k4];
        const float* e = &er[w][k4 * 4];
        a = fmaf(e[0], vv.x, a);
        a = fmaf(e[1], vv.y, a);
        a = fmaf(e[2], vv.z, a);
        a = fmaf(e[3], vv.w, a);
      }
      cval[w][c] = a;
    }

    // stable top-31 by (exact desc, idx asc) -> LDS kidx/kval
    for (int c = lane; c < cnt; c += 64) {
      float v = cval[w][c];
      int idx = cidx[w][c];
      int rnk = 0;
      for (int c2 = 0; c2 < cnt; ++c2) {
        float v2 = cval[w][c2];
        if (v2 > v || (v2 == v && cidx[w][c2] < idx)) ++rnk;
      }
      if (rnk < TOPK) {
        kidx[w][rnk] = idx;
        kval[w][rnk] = fmaxf(v, 0.0f);
      }
    }
  }

  // barrier drains all zero-stores (vmcnt 0) and publishes kidx/kval;
  // same-address ordering through L2 then serializes zero -> value.
  __syncthreads();

  if (ok && lane < TOPK) C[(size_t)row * NN + kidx[w][lane]] = kval[w][lane];
}

// ---------------------------------------------------------------------------
// Kernel D: exact cleanup for flagged rows (statistically never executes).
// ---------------------------------------------------------------------------
__global__ __launch_bounds__(256) void cleanup_kernel(
    float* __restrict__ C, const float* __restrict__ e32,
    const int* __restrict__ flags) {
  const int row = blockIdx.x;
  if (flags[row] == 0) return;
  const int tid = threadIdx.x;
  const int lane = tid & 63, wid = tid >> 6;

  __shared__ float sv[NN];
  __shared__ float er[DD];
  __shared__ unsigned long long wred[4];
  __shared__ int kidx[TOPK];
  __shared__ float kval[TOPK];

  {
    const float4* e4 = (const float4*)(e32 + (size_t)row * DD);
    if (tid < DD / 4) ((float4*)er)[tid] = e4[tid];
  }
  __syncthreads();

  for (int m = 0; m < NN / 256; ++m) {
    int j = m * 256 + tid;
    const float* ej = e32 + (size_t)j * DD;
    float a = 0.f;
    for (int k = 0; k < DD; k += 4) {
      float4 v = *(const float4*)&ej[k];
      a = fmaf(er[k], v.x, a);
      a = fmaf(er[k + 1], v.y, a);
      a = fmaf(er[k + 2], v.z, a);
      a = fmaf(er[k + 3], v.w, a);
    }
    sv[j] = a;
  }
  __syncthreads();

  for (int it = 0; it < TOPK; ++it) {
    float bv = -FLT_MAX;
    int bi = 0;
    for (int j = tid; j < NN; j += 256) {
      float v = sv[j];
      if (v > bv) { bv = v; bi = j; }
    }
    unsigned long long key =
        ((unsigned long long)ordmap(bv) << 32) | (unsigned)(NN - 1 - bi);
#pragma unroll
    for (int off = 32; off; off >>= 1) {
      unsigned long long o = __shfl_xor(key, off);
      if (o > key) key = o;
    }
    if (lane == 0) wred[wid] = key;
    __syncthreads();
    if (tid == 0) {
      unsigned long long k0 = wred[0];
      if (wred[1] > k0) k0 = wred[1];
      if (wred[2] > k0) k0 = wred[2];
      if (wred[3] > k0) k0 = wred[3];
      int idx = (NN - 1) - (int)(k0 & 0xFFFFFFFFu);
      kidx[it] = idx;
      kval[it] = sv[idx];
      sv[idx] = -FLT_MAX;
    }
    __syncthreads();
  }

  float4 z4 = make_float4(0.f, 0.f, 0.f, 0.f);
  float4* sv4 = (float4*)sv;
  for (int i = tid; i < NN / 4; i += 256) sv4[i] = z4;
  __syncthreads();
  if (tid < TOPK) sv[kidx[tid]] = fmaxf(kval[tid], 0.0f);
  __syncthreads();
  float4* Cw4 = (float4*)(C + (size_t)row * NN);
  for (int i = tid; i < NN / 4; i += 256) Cw4[i] = sv4[i];
}

// ---------------------------------------------------------------------------
extern "C" void kernel_launch(void* const* d_in, const int* in_sizes, int n_in,
                              void* d_out, int out_size, void* d_ws,
                              size_t ws_size, hipStream_t stream) {
  const float* f = (const float*)d_in[0];
  const float* W1 = (const float*)d_in[1];
  const float* W2 = (const float*)d_in[2];
  float* out = (float*)d_out;
  char* ws = (char*)d_ws;
  float* e32 = (float*)ws;                                     // 16 MiB
  unsigned short* Ehi = (unsigned short*)(ws + (size_t)NN * DD * 4);   // 8 MiB
  unsigned short* Elo = (unsigned short*)(ws + (size_t)NN * DD * 6);   // 8 MiB
  float* TM = (float*)(ws + (size_t)NN * DD * 8);              // 2 MiB
  int* flags = (int*)(ws + (size_t)NN * DD * 8 + (size_t)NN * 64 * 4);  // 32 KB

  emb_kernel<<<NN / 4, 256, 0, stream>>>(f, W1, W2, e32, Ehi, Elo, flags);
  sim_mfma<<<2080, 512, 0, stream>>>(Ehi, Elo, out, TM);
  topk_collect<<<NN / 4, 256, 0, stream>>>(out, e32, TM, flags);
  cleanup_kernel<<<NN, 256, 0, stream>>>(out, e32, flags);
}

// Round 12
// 531.169 us; speedup vs baseline: 1.1308x; 1.1308x over previous
//
#include <hip/hip_runtime.h>
#include <float.h>
#include <math.h>

// Problem constants (fixed by the reference: N=8192, D=512, k+1=31).
#define NN 8192
#define DD 512
#define TOPK 31
#define CAPW 256          // per-row candidate cap (typical cnt ~105 now)
#define DELTA 1.25e-3f    // sound |fp16-1-term approx - exact| bound:
                          // 2*2^-11*||e||^2 (9.8e-4) + f32 accum (~6e-5)

// Strategy (R19 = R18's fp16 single-term sim on R15's SAFE barrier loop):
//   Bit-exact value chain (absmax 0.0 since R3):
//     h = relu(f*W1)*W2 ; n = sqrtf(numpy-pairwise sum h*h) ; e = h/n
//     sim[i][j] = sequential-k fmaf chain over e_i*e_j ; stable top-31
//   Approx sim = ONE fp16 MFMA term (f32 accumulate; fp16 x fp16 products
//   are exact in f32). DELTA=1.25e-3 sound -> threshold width 2.5e-3.
//   sim: 128x128 tile, 4 waves, 2-phase double-buffered global_load_lds
//   with R15's single __syncthreads per k-step (compiler vmcnt(0) drain --
//   R18's counted vmcnt(4)+raw-barrier raced: compiler can break the count;
//   tripwire caught timing-dependent divergence). Bijective XCD swizzle.
//   LDS 2x16KB -> 4 blocks/CU. f32 acc -> round-up bf16 scratch in the
//   SECOND 16KB of each output f32 row + per-row tile maxima TM.
//   collect (1 wave/row): tile-skip scan (tmax < Tc -> skip loads; sound),
//   zero BOTH row halves during scan, exact fmaf chains re-rank to LDS,
//   scatter 31 values after the barrier. cleanup rewrites flagged rows.

typedef __attribute__((ext_vector_type(8))) short short8;
typedef __attribute__((ext_vector_type(8))) _Float16 half8;
typedef __attribute__((ext_vector_type(4))) float f32x4;

__device__ __forceinline__ float h_elem(const float* __restrict__ f,
                                        const float* __restrict__ W1,
                                        const float* __restrict__ W2, int k) {
  float x = f[k] * W1[k];
  x = fmaxf(x, 0.0f);
  return x * W2[k];
}

// Round toward +inf: guarantees bf16(x) >= x. (pos: ceil; neg: trunc->up)
__device__ __forceinline__ unsigned short f2bf_ru(float x) {
  unsigned u = __float_as_uint(x);
  if (!(u >> 31)) u += 0xffffu;
  return (unsigned short)(u >> 16);
}
__device__ __forceinline__ unsigned ordmap(float x) {
  unsigned u = __float_as_uint(x);
  return (u & 0x80000000u) ? ~u : (u | 0x80000000u);
}

// async global->LDS, 16B per lane (dest = wave-uniform base + lane*16)
__device__ __forceinline__ void gl16(const void* g, void* l) {
  __builtin_amdgcn_global_load_lds(
      (const __attribute__((address_space(1))) void*)g,
      (__attribute__((address_space(3))) void*)l, 16, 0, 0);
}

// bf16 scratch image of sim row i: second half of output row i's 32KB span.
__device__ __forceinline__ unsigned short* bfrow(float* C, int row) {
  return (unsigned short*)C + (size_t)row * (2 * NN) + NN;
}

// ---------------------------------------------------------------------------
// Kernel A: fused norm (numpy pairwise association, bit-exact) + e = h/n,
// fp16 image (RNE via cast), flag zeroing. One wave per row.
// ---------------------------------------------------------------------------
__global__ __launch_bounds__(256) void emb_kernel(
    const float* __restrict__ f, const float* __restrict__ W1,
    const float* __restrict__ W2, float* __restrict__ e32,
    _Float16* __restrict__ Ef, int* __restrict__ flags) {
  const int lane = threadIdx.x & 63;
  const int row = blockIdx.x * 4 + (threadIdx.x >> 6);
  const float* fr = f + (size_t)row * DD;
  const int b = lane >> 4, L = lane & 15;
  if (lane == 0) flags[row] = 0;

  float s[8];
#pragma unroll
  for (int j = 0; j < 8; ++j) {
    float h = h_elem(fr, W1, W2, b * 128 + 16 * j + L);
    s[j] = h * h;
  }
  float v = ((s[0] + s[1]) + (s[2] + s[3])) + ((s[4] + s[5]) + (s[6] + s[7]));
  float t = v + __shfl_xor(v, 8);
  t = t + __shfl_xor(t, 4);
  t = t + __shfl_xor(t, 2);
  float nb = t + __shfl_xor(t, 1);
  float x = nb + __shfl_xor(nb, 16);
  float norm2 = x + __shfl_xor(x, 32);
  const float n = fmaxf(sqrtf(norm2), 1e-12f);

  float* er = e32 + (size_t)row * DD;
  _Float16* hr = Ef + (size_t)row * DD;
#pragma unroll
  for (int m = 0; m < 8; ++m) {
    int k = m * 64 + lane;
    float e = h_elem(fr, W1, W2, k) / n;
    er[k] = e;
    hr[k] = (_Float16)e;  // RNE
  }
}

// ---------------------------------------------------------------------------
// Kernel B: single-term fp16 MFMA sim, upper-triangle 128x128 tiles.
// R15-safe 2-phase K-loop (BK=32): STAGE(next buf: 4 gl16) -> 8 frag reads
// + 16 MFMAs (cur buf) -> ONE __syncthreads (its vmcnt(0) drain lands after
// the MFMAs covered the load latency; unconditionally race-free).
// Linear LDS tiles A|B (8KB each) x 2 buffers (32KB).
// Epilogue: round-up bf16 tile write into per-row scratch halves + per-row
// tile-max TM + (bx>by) transposed mirror tile via LDS strips + transposed TM.
// ---------------------------------------------------------------------------
#define OFS_B 4096    // short offset of B tile within a buffer

#define STAGE(BUF, KK)                       \
  do {                                       \
    char* Ld = L0 + ((BUF) << 14);           \
    gl16(Ef + rA + (KK), Ld);                \
    gl16(Ef + rA + H + (KK), Ld + 4096);     \
    gl16(Ef + rB + (KK), Ld + 8192);         \
    gl16(Ef + rB + H + (KK), Ld + 12288);    \
  } while (0)

__global__ __launch_bounds__(256) void sim_mfma(
    const _Float16* __restrict__ Ef, float* __restrict__ C,
    float* __restrict__ TM) {
  // bijective XCD swizzle (2080 % 8 == 0): consecutive swz within an XCD
  // share the by-band -> A-panel L2 locality on the XCD's private L2.
  int swz = (blockIdx.x & 7) * 260 + (blockIdx.x >> 3);
  // triangular decode: 2080 -> (bx, by) with bx >= by
  int rem = swz, by = 0;
  while (rem >= 64 - by) { rem -= 64 - by; ++by; }
  const int bx = by + rem;

  __shared__ __align__(16) char smem[34048];  // 2 x 16KB ping-pong; epi alias
  unsigned short* S = (unsigned short*)smem;
  char* Sc = smem;
  float(*Tt)[133] = (float(*)[133])smem;  // epilogue alias ([64][133] = 34048B)
  __shared__ float rmx[128][2];
  __shared__ float cmx[128][2];

  const int t = threadIdx.x;
  const int lane = t & 63, w = t >> 6;
  const int wr = w >> 1, wc = w & 1;
  const int quad = lane >> 4, l16 = lane & 15;
  const int i0 = by * 128, j0 = bx * 128;

  f32x4 acc[4][4];
#pragma unroll
  for (int a = 0; a < 4; ++a)
#pragma unroll
    for (int b = 0; b < 4; ++b) acc[a][b] = (f32x4){0.f, 0.f, 0.f, 0.f};

  // staging: thread t writes LDS bytes [t*16, t*16+16) of each 4KB tensor-half
  // == row (t>>2), chunk (t&3) of a linear [128][32-half] tile.
  const size_t rA = (size_t)(i0 + (t >> 2)) * DD + (t & 3) * 8;
  const size_t rB = (size_t)(j0 + (t >> 2)) * DD + (t & 3) * 8;
  const size_t H = (size_t)64 * DD;
  char* L0 = Sc + (w << 10);  // wave-uniform LDS base

  STAGE(0, 0);
  __syncthreads();

  int cur = 0;
  for (int kk = 0; kk < DD; kk += 32) {
    if (kk + 32 < DD) STAGE(cur ^ 1, kk + 32);  // issue next tile's loads

    const unsigned short* Sb = S + (cur << 13);  // cur*8192 shorts
    half8 ah[4], bh[4];
#pragma unroll
    for (int mt = 0; mt < 4; ++mt)
      ah[mt] = *(const half8*)&Sb[(wr * 64 + mt * 16 + l16) * 32 + quad * 8];
#pragma unroll
    for (int nt = 0; nt < 4; ++nt)
      bh[nt] = *(const half8*)&Sb[OFS_B + (wc * 64 + nt * 16 + l16) * 32 + quad * 8];
#pragma unroll
    for (int mt = 0; mt < 4; ++mt)
#pragma unroll
      for (int nt = 0; nt < 4; ++nt)
        acc[mt][nt] = __builtin_amdgcn_mfma_f32_16x16x32_f16(ah[mt], bh[nt], acc[mt][nt], 0, 0, 0);

    __syncthreads();  // drains next-buf loads + all waves done reading cur
    cur ^= 1;
  }

  // --- normal tile write: round-up bf16 into per-row scratch ---
#pragma unroll
  for (int mt = 0; mt < 4; ++mt)
#pragma unroll
    for (int r = 0; r < 4; ++r) {
      int row = i0 + wr * 64 + mt * 16 + quad * 4 + r;
      unsigned short* Br = bfrow(C, row) + j0 + wc * 64;
#pragma unroll
      for (int nt = 0; nt < 4; ++nt) Br[nt * 16 + l16] = f2bf_ru(acc[mt][nt][r]);
    }

  // --- per-row tile-max (rows of this tile) ---
#pragma unroll
  for (int mt = 0; mt < 4; ++mt)
#pragma unroll
    for (int r = 0; r < 4; ++r) {
      float m = fmaxf(fmaxf(acc[mt][0][r], acc[mt][1][r]),
                      fmaxf(acc[mt][2][r], acc[mt][3][r]));
      m = fmaxf(m, __shfl_xor(m, 1));
      m = fmaxf(m, __shfl_xor(m, 2));
      m = fmaxf(m, __shfl_xor(m, 4));
      m = fmaxf(m, __shfl_xor(m, 8));
      if (l16 == 0) rmx[wr * 64 + mt * 16 + quad * 4 + r][wc] = m;
    }
  // --- per-col tile-max (rows of the mirrored tile), only if off-diagonal ---
  if (bx > by) {
#pragma unroll
    for (int nt = 0; nt < 4; ++nt) {
      float c = -FLT_MAX;
#pragma unroll
      for (int mt = 0; mt < 4; ++mt)
#pragma unroll
        for (int r = 0; r < 4; ++r) c = fmaxf(c, acc[mt][nt][r]);
      c = fmaxf(c, __shfl_xor(c, 16));
      c = fmaxf(c, __shfl_xor(c, 32));
      if (quad == 0) cmx[wc * 64 + nt * 16 + l16][wr] = c;
    }
  }
  __syncthreads();
  if (t < 128) TM[(size_t)(i0 + t) * 64 + bx] = fmaxf(rmx[t][0], rmx[t][1]);
  if (bx > by) {
    if (t < 128) TM[(size_t)(j0 + t) * 64 + by] = fmaxf(cmx[t][0], cmx[t][1]);
    // --- transposed mirror write via LDS strips (Tt aliases S), bf16-RU out ---
    for (int s = 0; s < 2; ++s) {
      __syncthreads();
      if (wc == s) {
#pragma unroll
        for (int mt = 0; mt < 4; ++mt)
#pragma unroll
          for (int nt = 0; nt < 4; ++nt)
#pragma unroll
            for (int r = 0; r < 4; ++r)
              Tt[nt * 16 + l16][wr * 64 + mt * 16 + quad * 4 + r] = acc[mt][nt][r];
      }
      __syncthreads();
#pragma unroll
      for (int q = 0; q < 8; ++q) {
        int fi = q * 256 + t;
        int rr = fi >> 5;
        int cc4 = (fi & 31) * 4;
        ushort4 v;
        v.x = f2bf_ru(Tt[rr][cc4]);
        v.y = f2bf_ru(Tt[rr][cc4 + 1]);
        v.z = f2bf_ru(Tt[rr][cc4 + 2]);
        v.w = f2bf_ru(Tt[rr][cc4 + 3]);
        *(ushort4*)(bfrow(C, j0 + s * 64 + rr) + i0 + cc4) = v;
      }
    }
  }
}

// ---------------------------------------------------------------------------
// Kernel C: collect+write. One WAVE per row (4 rows/block). T = 31st largest
// tile-max via O(64) rank-select. Single pass over the bf16-RU row scratch:
// SKIP loads for tiles with tmax < Tc (sound; output-identical), collect
// cands >= T - 2*DELTA, zero BOTH halves of the output row. Exact fmaf
// chains re-rank into LDS kidx/kval; __syncthreads (vmcnt drain: zeros
// committed); lanes 0..30 scatter the 31 final values. Overflow -> flag,
// predicated skip (zeros already written; cleanup rewrites the row).
// ---------------------------------------------------------------------------
__global__ __launch_bounds__(256) void topk_collect(
    float* __restrict__ C, const float* __restrict__ e32,
    const float* __restrict__ TM, int* __restrict__ flags) {
  const int w = threadIdx.x >> 6;
  const int lane = threadIdx.x & 63;
  const int row = blockIdx.x * 4 + w;

  __shared__ float er[4][DD];
  __shared__ int cidx[4][CAPW];
  __shared__ float cval[4][CAPW];
  __shared__ int wcnt[4];
  __shared__ int kidx[4][TOPK];
  __shared__ float kval[4][TOPK];

  {
    const float4* e4 = (const float4*)(e32 + (size_t)row * DD);
    float4* er4 = (float4*)er[w];
    er4[lane] = e4[lane];
    er4[64 + lane] = e4[64 + lane];
  }
  if (lane == 0) wcnt[w] = 0;

  // T = 31st largest of 64 tile maxima: rank-select with independent shuffles.
  const float mv = TM[(size_t)row * 64 + lane];  // preserved for tile-skip
  unsigned key = ordmap(mv);
  int rank = 0;
#pragma unroll
  for (int off = 1; off < 64; ++off) {
    int ol = (lane + off) & 63;
    unsigned ok2 = __shfl(key, ol);
    rank += (ok2 > key || (ok2 == key && ol < lane)) ? 1 : 0;
  }
  unsigned long long bmsk = __ballot(rank == TOPK - 1);
  float T = __shfl(mv, __ffsll((unsigned long long)bmsk) - 1);

  // single row pass: tile-skip scan + candidates + zero BOTH row halves
  const float Tc = T - 2.0f * DELTA;
  unsigned short* Brow = bfrow(C, row);
  const uint4* Br4 = (const uint4*)Brow;
  uint4* Bw4 = (uint4*)Brow;                      // scratch half (16KB)
  float4* Zw4 = (float4*)(C + (size_t)row * NN);  // first 16KB = 1024 float4
  const float4 z4 = make_float4(0.f, 0.f, 0.f, 0.f);
  const uint4 zu4 = {0u, 0u, 0u, 0u};
  for (int it = 0; it < NN / 512; ++it) {
    // lane's 8 columns this iteration lie in tile it*4 + (lane>>4)
    const float tmx = __shfl(mv, it * 4 + (lane >> 4));
    const bool live = (tmx >= Tc);
    uint4 v = zu4;
    if (live) v = Br4[it * 64 + lane];
    Zw4[it * 64 + lane] = z4;
    Bw4[it * 64 + lane] = zu4;
    if (live) {
      int j = (it * 64 + lane) * 8;
      unsigned wv[4] = {v.x, v.y, v.z, v.w};
#pragma unroll
      for (int c = 0; c < 4; ++c) {
        float f0 = __uint_as_float(wv[c] << 16);
        float f1 = __uint_as_float(wv[c] & 0xffff0000u);
        if (f0 >= Tc) { int p = atomicAdd(&wcnt[w], 1); if (p < CAPW) cidx[w][p] = j + 2 * c; }
        if (f1 >= Tc) { int p = atomicAdd(&wcnt[w], 1); if (p < CAPW) cidx[w][p] = j + 2 * c + 1; }
      }
    }
  }
  const int cnt = wcnt[w];
  const bool ok = (cnt <= CAPW);
  if (!ok && lane == 0) flags[row] = 1;

  // exact sequential-k fmaf chains (bit-identical to the verified chain)
  if (ok) {
    for (int c = lane; c < cnt; c += 64) {
      const float4* ej4 = (const float4*)(e32 + (size_t)cidx[w][c] * DD);
      float a = 0.f;
      for (int k4 = 0; k4 < DD / 4; ++k4) {
        float4 vv = ej4[k4];
        const float* e = &er[w][k4 * 4];
        a = fmaf(e[0], vv.x, a);
        a = fmaf(e[1], vv.y, a);
        a = fmaf(e[2], vv.z, a);
        a = fmaf(e[3], vv.w, a);
      }
      cval[w][c] = a;
    }

    // stable top-31 by (exact desc, idx asc) -> LDS kidx/kval
    for (int c = lane; c < cnt; c += 64) {
      float v = cval[w][c];
      int idx = cidx[w][c];
      int rnk = 0;
      for (int c2 = 0; c2 < cnt; ++c2) {
        float v2 = cval[w][c2];
        if (v2 > v || (v2 == v && cidx[w][c2] < idx)) ++rnk;
      }
      if (rnk < TOPK) {
        kidx[w][rnk] = idx;
        kval[w][rnk] = fmaxf(v, 0.0f);
      }
    }
  }

  // barrier drains all zero-stores (vmcnt 0) and publishes kidx/kval;
  // same-address ordering through L2 then serializes zero -> value.
  __syncthreads();

  if (ok && lane < TOPK) C[(size_t)row * NN + kidx[w][lane]] = kval[w][lane];
}

// ---------------------------------------------------------------------------
// Kernel D: exact cleanup for flagged rows (statistically never executes).
// ---------------------------------------------------------------------------
__global__ __launch_bounds__(256) void cleanup_kernel(
    float* __restrict__ C, const float* __restrict__ e32,
    const int* __restrict__ flags) {
  const int row = blockIdx.x;
  if (flags[row] == 0) return;
  const int tid = threadIdx.x;
  const int lane = tid & 63, wid = tid >> 6;

  __shared__ float sv[NN];
  __shared__ float er[DD];
  __shared__ unsigned long long wred[4];
  __shared__ int kidx[TOPK];
  __shared__ float kval[TOPK];

  {
    const float4* e4 = (const float4*)(e32 + (size_t)row * DD);
    if (tid < DD / 4) ((float4*)er)[tid] = e4[tid];
  }
  __syncthreads();

  for (int m = 0; m < NN / 256; ++m) {
    int j = m * 256 + tid;
    const float* ej = e32 + (size_t)j * DD;
    float a = 0.f;
    for (int k = 0; k < DD; k += 4) {
      float4 v = *(const float4*)&ej[k];
      a = fmaf(er[k], v.x, a);
      a = fmaf(er[k + 1], v.y, a);
      a = fmaf(er[k + 2], v.z, a);
      a = fmaf(er[k + 3], v.w, a);
    }
    sv[j] = a;
  }
  __syncthreads();

  for (int it = 0; it < TOPK; ++it) {
    float bv = -FLT_MAX;
    int bi = 0;
    for (int j = tid; j < NN; j += 256) {
      float v = sv[j];
      if (v > bv) { bv = v; bi = j; }
    }
    unsigned long long key =
        ((unsigned long long)ordmap(bv) << 32) | (unsigned)(NN - 1 - bi);
#pragma unroll
    for (int off = 32; off; off >>= 1) {
      unsigned long long o = __shfl_xor(key, off);
      if (o > key) key = o;
    }
    if (lane == 0) wred[wid] = key;
    __syncthreads();
    if (tid == 0) {
      unsigned long long k0 = wred[0];
      if (wred[1] > k0) k0 = wred[1];
      if (wred[2] > k0) k0 = wred[2];
      if (wred[3] > k0) k0 = wred[3];
      int idx = (NN - 1) - (int)(k0 & 0xFFFFFFFFu);
      kidx[it] = idx;
      kval[it] = sv[idx];
      sv[idx] = -FLT_MAX;
    }
    __syncthreads();
  }

  float4 z4 = make_float4(0.f, 0.f, 0.f, 0.f);
  float4* sv4 = (float4*)sv;
  for (int i = tid; i < NN / 4; i += 256) sv4[i] = z4;
  __syncthreads();
  if (tid < TOPK) sv[kidx[tid]] = fmaxf(kval[tid], 0.0f);
  __syncthreads();
  float4* Cw4 = (float4*)(C + (size_t)row * NN);
  for (int i = tid; i < NN / 4; i += 256) Cw4[i] = sv4[i];
}

// ---------------------------------------------------------------------------
extern "C" void kernel_launch(void* const* d_in, const int* in_sizes, int n_in,
                              void* d_out, int out_size, void* d_ws,
                              size_t ws_size, hipStream_t stream) {
  const float* f = (const float*)d_in[0];
  const float* W1 = (const float*)d_in[1];
  const float* W2 = (const float*)d_in[2];
  float* out = (float*)d_out;
  char* ws = (char*)d_ws;
  float* e32 = (float*)ws;                                     // 16 MiB
  _Float16* Ef = (_Float16*)(ws + (size_t)NN * DD * 4);        // 8 MiB
  float* TM = (float*)(ws + (size_t)NN * DD * 6);              // 2 MiB
  int* flags = (int*)(ws + (size_t)NN * DD * 6 + (size_t)NN * 64 * 4);  // 32 KB

  emb_kernel<<<NN / 4, 256, 0, stream>>>(f, W1, W2, e32, Ef, flags);
  sim_mfma<<<2080, 256, 0, stream>>>(Ef, out, TM);
  topk_collect<<<NN / 4, 256, 0, stream>>>(out, e32, TM, flags);
  cleanup_kernel<<<NN, 256, 0, stream>>>(out, e32, flags);
}

// Round 13
// 510.492 us; speedup vs baseline: 1.1766x; 1.0405x over previous
//
#include <hip/hip_runtime.h>
#include <float.h>
#include <math.h>

// Problem constants (fixed by the reference: N=8192, D=512, k+1=31).
#define NN 8192
#define DD 512
#define TOPK 31
#define CAPW 192          // per-row candidate cap (typical cnt ~40 now)
#define DELTA 1.25e-3f    // sound |fp16-1-term approx - exact| bound:
                          // 2*2^-11*||e||^2 (9.8e-4) + f32 accum (~6e-5)

// Strategy (R20 = R19 + fp16-RU scratch, halves the scan-threshold width):
//   Bit-exact value chain (absmax 0.0 since R3):
//     h = relu(f*W1)*W2 ; n = sqrtf(numpy-pairwise sum h*h) ; e = h/n
//     sim[i][j] = sequential-k fmaf chain over e_i*e_j ; stable top-31
//   Approx sim = ONE fp16 MFMA term (f32 accumulate). Scratch stored as
//   ROUND-UP fp16 (ulp ~9.8e-4 near 1.0 vs bf16's 3.9e-3): effective
//   candidate width = 2*DELTA + ulp = 3.5e-3 (was 6.4e-3) -> cnt ~105->~40.
//   Density model (R4/R13/R19 fits): ~23 cands per 1e-3 width.
//   sim: 128x128 tile, 4 waves, 2-phase double-buffered global_load_lds,
//   single __syncthreads per k-step (race-free; R18's counted vmcnt raced),
//   bijective XCD swizzle, LDS 2x16KB -> 4 blocks/CU. f32 acc -> fp16-RU
//   scratch in the SECOND 16KB of each output f32 row + tile maxima TM.
//   collect (1 wave/row): tile-skip scan (tmax < Tc -> skip loads; sound),
//   zero BOTH row halves during scan, exact fmaf chains re-rank to LDS,
//   scatter 31 values after the barrier. cleanup rewrites flagged rows.

typedef __attribute__((ext_vector_type(8))) short short8;
typedef __attribute__((ext_vector_type(8))) _Float16 half8;
typedef __attribute__((ext_vector_type(4))) float f32x4;

__device__ __forceinline__ float h_elem(const float* __restrict__ f,
                                        const float* __restrict__ W1,
                                        const float* __restrict__ W2, int k) {
  float x = f[k] * W1[k];
  x = fmaxf(x, 0.0f);
  return x * W2[k];
}

// fp16 round-toward-+inf: guarantees decode(f2h_ru(x)) >= x.
// RNE cast, then bump one ulp away-from-(-inf) if it landed below x.
__device__ __forceinline__ unsigned short f2h_ru(float x) {
  _Float16 h = (_Float16)x;  // RNE
  unsigned short b = __builtin_bit_cast(unsigned short, h);
  if ((float)h < x) b = (b & 0x8000u) ? (unsigned short)(b - 1)
                                      : (unsigned short)(b + 1);
  return b;
}
__device__ __forceinline__ float h2f(unsigned short b) {
  return (float)__builtin_bit_cast(_Float16, b);
}
__device__ __forceinline__ unsigned ordmap(float x) {
  unsigned u = __float_as_uint(x);
  return (u & 0x80000000u) ? ~u : (u | 0x80000000u);
}

// async global->LDS, 16B per lane (dest = wave-uniform base + lane*16)
__device__ __forceinline__ void gl16(const void* g, void* l) {
  __builtin_amdgcn_global_load_lds(
      (const __attribute__((address_space(1))) void*)g,
      (__attribute__((address_space(3))) void*)l, 16, 0, 0);
}

// fp16 scratch image of sim row i: second half of output row i's 32KB span.
__device__ __forceinline__ unsigned short* hrow(float* C, int row) {
  return (unsigned short*)C + (size_t)row * (2 * NN) + NN;
}

// ---------------------------------------------------------------------------
// Kernel A: fused norm (numpy pairwise association, bit-exact) + e = h/n,
// fp16 image (RNE via cast), flag zeroing. One wave per row.
// ---------------------------------------------------------------------------
__global__ __launch_bounds__(256) void emb_kernel(
    const float* __restrict__ f, const float* __restrict__ W1,
    const float* __restrict__ W2, float* __restrict__ e32,
    _Float16* __restrict__ Ef, int* __restrict__ flags) {
  const int lane = threadIdx.x & 63;
  const int row = blockIdx.x * 4 + (threadIdx.x >> 6);
  const float* fr = f + (size_t)row * DD;
  const int b = lane >> 4, L = lane & 15;
  if (lane == 0) flags[row] = 0;

  float s[8];
#pragma unroll
  for (int j = 0; j < 8; ++j) {
    float h = h_elem(fr, W1, W2, b * 128 + 16 * j + L);
    s[j] = h * h;
  }
  float v = ((s[0] + s[1]) + (s[2] + s[3])) + ((s[4] + s[5]) + (s[6] + s[7]));
  float t = v + __shfl_xor(v, 8);
  t = t + __shfl_xor(t, 4);
  t = t + __shfl_xor(t, 2);
  float nb = t + __shfl_xor(t, 1);
  float x = nb + __shfl_xor(nb, 16);
  float norm2 = x + __shfl_xor(x, 32);
  const float n = fmaxf(sqrtf(norm2), 1e-12f);

  float* er = e32 + (size_t)row * DD;
  _Float16* hr = Ef + (size_t)row * DD;
#pragma unroll
  for (int m = 0; m < 8; ++m) {
    int k = m * 64 + lane;
    float e = h_elem(fr, W1, W2, k) / n;
    er[k] = e;
    hr[k] = (_Float16)e;  // RNE
  }
}

// ---------------------------------------------------------------------------
// Kernel B: single-term fp16 MFMA sim, upper-triangle 128x128 tiles.
// R15-safe 2-phase K-loop (BK=32): STAGE(next buf: 4 gl16) -> 8 frag reads
// + 16 MFMAs (cur buf) -> ONE __syncthreads (its vmcnt(0) drain lands after
// the MFMAs covered the load latency; unconditionally race-free).
// Linear LDS tiles A|B (8KB each) x 2 buffers (32KB).
// Epilogue: round-up fp16 tile write into per-row scratch halves + per-row
// tile-max TM + (bx>by) transposed mirror tile via LDS strips + transposed TM.
// ---------------------------------------------------------------------------
#define OFS_B 4096    // short offset of B tile within a buffer

#define STAGE(BUF, KK)                       \
  do {                                       \
    char* Ld = L0 + ((BUF) << 14);           \
    gl16(Ef + rA + (KK), Ld);                \
    gl16(Ef + rA + H + (KK), Ld + 4096);     \
    gl16(Ef + rB + (KK), Ld + 8192);         \
    gl16(Ef + rB + H + (KK), Ld + 12288);    \
  } while (0)

__global__ __launch_bounds__(256) void sim_mfma(
    const _Float16* __restrict__ Ef, float* __restrict__ C,
    float* __restrict__ TM) {
  // bijective XCD swizzle (2080 % 8 == 0): consecutive swz within an XCD
  // share the by-band -> A-panel L2 locality on the XCD's private L2.
  int swz = (blockIdx.x & 7) * 260 + (blockIdx.x >> 3);
  // triangular decode: 2080 -> (bx, by) with bx >= by
  int rem = swz, by = 0;
  while (rem >= 64 - by) { rem -= 64 - by; ++by; }
  const int bx = by + rem;

  __shared__ __align__(16) char smem[34048];  // 2 x 16KB ping-pong; epi alias
  unsigned short* S = (unsigned short*)smem;
  char* Sc = smem;
  float(*Tt)[133] = (float(*)[133])smem;  // epilogue alias ([64][133] = 34048B)
  __shared__ float rmx[128][2];
  __shared__ float cmx[128][2];

  const int t = threadIdx.x;
  const int lane = t & 63, w = t >> 6;
  const int wr = w >> 1, wc = w & 1;
  const int quad = lane >> 4, l16 = lane & 15;
  const int i0 = by * 128, j0 = bx * 128;

  f32x4 acc[4][4];
#pragma unroll
  for (int a = 0; a < 4; ++a)
#pragma unroll
    for (int b = 0; b < 4; ++b) acc[a][b] = (f32x4){0.f, 0.f, 0.f, 0.f};

  // staging: thread t writes LDS bytes [t*16, t*16+16) of each 4KB tensor-half
  // == row (t>>2), chunk (t&3) of a linear [128][32-half] tile.
  const size_t rA = (size_t)(i0 + (t >> 2)) * DD + (t & 3) * 8;
  const size_t rB = (size_t)(j0 + (t >> 2)) * DD + (t & 3) * 8;
  const size_t H = (size_t)64 * DD;
  char* L0 = Sc + (w << 10);  // wave-uniform LDS base

  STAGE(0, 0);
  __syncthreads();

  int cur = 0;
  for (int kk = 0; kk < DD; kk += 32) {
    if (kk + 32 < DD) STAGE(cur ^ 1, kk + 32);  // issue next tile's loads

    const unsigned short* Sb = S + (cur << 13);  // cur*8192 shorts
    half8 ah[4], bh[4];
#pragma unroll
    for (int mt = 0; mt < 4; ++mt)
      ah[mt] = *(const half8*)&Sb[(wr * 64 + mt * 16 + l16) * 32 + quad * 8];
#pragma unroll
    for (int nt = 0; nt < 4; ++nt)
      bh[nt] = *(const half8*)&Sb[OFS_B + (wc * 64 + nt * 16 + l16) * 32 + quad * 8];
#pragma unroll
    for (int mt = 0; mt < 4; ++mt)
#pragma unroll
      for (int nt = 0; nt < 4; ++nt)
        acc[mt][nt] = __builtin_amdgcn_mfma_f32_16x16x32_f16(ah[mt], bh[nt], acc[mt][nt], 0, 0, 0);

    __syncthreads();  // drains next-buf loads + all waves done reading cur
    cur ^= 1;
  }

  // --- normal tile write: round-up fp16 into per-row scratch ---
#pragma unroll
  for (int mt = 0; mt < 4; ++mt)
#pragma unroll
    for (int r = 0; r < 4; ++r) {
      int row = i0 + wr * 64 + mt * 16 + quad * 4 + r;
      unsigned short* Br = hrow(C, row) + j0 + wc * 64;
#pragma unroll
      for (int nt = 0; nt < 4; ++nt) Br[nt * 16 + l16] = f2h_ru(acc[mt][nt][r]);
    }

  // --- per-row tile-max (rows of this tile) ---
#pragma unroll
  for (int mt = 0; mt < 4; ++mt)
#pragma unroll
    for (int r = 0; r < 4; ++r) {
      float m = fmaxf(fmaxf(acc[mt][0][r], acc[mt][1][r]),
                      fmaxf(acc[mt][2][r], acc[mt][3][r]));
      m = fmaxf(m, __shfl_xor(m, 1));
      m = fmaxf(m, __shfl_xor(m, 2));
      m = fmaxf(m, __shfl_xor(m, 4));
      m = fmaxf(m, __shfl_xor(m, 8));
      if (l16 == 0) rmx[wr * 64 + mt * 16 + quad * 4 + r][wc] = m;
    }
  // --- per-col tile-max (rows of the mirrored tile), only if off-diagonal ---
  if (bx > by) {
#pragma unroll
    for (int nt = 0; nt < 4; ++nt) {
      float c = -FLT_MAX;
#pragma unroll
      for (int mt = 0; mt < 4; ++mt)
#pragma unroll
        for (int r = 0; r < 4; ++r) c = fmaxf(c, acc[mt][nt][r]);
      c = fmaxf(c, __shfl_xor(c, 16));
      c = fmaxf(c, __shfl_xor(c, 32));
      if (quad == 0) cmx[wc * 64 + nt * 16 + l16][wr] = c;
    }
  }
  __syncthreads();
  if (t < 128) TM[(size_t)(i0 + t) * 64 + bx] = fmaxf(rmx[t][0], rmx[t][1]);
  if (bx > by) {
    if (t < 128) TM[(size_t)(j0 + t) * 64 + by] = fmaxf(cmx[t][0], cmx[t][1]);
    // --- transposed mirror write via LDS strips (Tt aliases S), fp16-RU out ---
    for (int s = 0; s < 2; ++s) {
      __syncthreads();
      if (wc == s) {
#pragma unroll
        for (int mt = 0; mt < 4; ++mt)
#pragma unroll
          for (int nt = 0; nt < 4; ++nt)
#pragma unroll
            for (int r = 0; r < 4; ++r)
              Tt[nt * 16 + l16][wr * 64 + mt * 16 + quad * 4 + r] = acc[mt][nt][r];
      }
      __syncthreads();
#pragma unroll
      for (int q = 0; q < 8; ++q) {
        int fi = q * 256 + t;
        int rr = fi >> 5;
        int cc4 = (fi & 31) * 4;
        ushort4 v;
        v.x = f2h_ru(Tt[rr][cc4]);
        v.y = f2h_ru(Tt[rr][cc4 + 1]);
        v.z = f2h_ru(Tt[rr][cc4 + 2]);
        v.w = f2h_ru(Tt[rr][cc4 + 3]);
        *(ushort4*)(hrow(C, j0 + s * 64 + rr) + i0 + cc4) = v;
      }
    }
  }
}

// ---------------------------------------------------------------------------
// Kernel C: collect+write. One WAVE per row (4 rows/block). T = 31st largest
// tile-max via O(64) rank-select. Single pass over the fp16-RU row scratch:
// SKIP loads for tiles with tmax < Tc (sound; output-identical), collect
// cands >= T - 2*DELTA, zero BOTH halves of the output row. Exact fmaf
// chains re-rank into LDS kidx/kval; __syncthreads (vmcnt drain: zeros
// committed); lanes 0..30 scatter the 31 final values. Overflow -> flag,
// predicated skip (zeros already written; cleanup rewrites the row).
// ---------------------------------------------------------------------------
__global__ __launch_bounds__(256) void topk_collect(
    float* __restrict__ C, const float* __restrict__ e32,
    const float* __restrict__ TM, int* __restrict__ flags) {
  const int w = threadIdx.x >> 6;
  const int lane = threadIdx.x & 63;
  const int row = blockIdx.x * 4 + w;

  __shared__ float er[4][DD];
  __shared__ int cidx[4][CAPW];
  __shared__ float cval[4][CAPW];
  __shared__ int wcnt[4];
  __shared__ int kidx[4][TOPK];
  __shared__ float kval[4][TOPK];

  {
    const float4* e4 = (const float4*)(e32 + (size_t)row * DD);
    float4* er4 = (float4*)er[w];
    er4[lane] = e4[lane];
    er4[64 + lane] = e4[64 + lane];
  }
  if (lane == 0) wcnt[w] = 0;

  // T = 31st largest of 64 tile maxima: rank-select with independent shuffles.
  const float mv = TM[(size_t)row * 64 + lane];  // preserved for tile-skip
  unsigned key = ordmap(mv);
  int rank = 0;
#pragma unroll
  for (int off = 1; off < 64; ++off) {
    int ol = (lane + off) & 63;
    unsigned ok2 = __shfl(key, ol);
    rank += (ok2 > key || (ok2 == key && ol < lane)) ? 1 : 0;
  }
  unsigned long long bmsk = __ballot(rank == TOPK - 1);
  float T = __shfl(mv, __ffsll((unsigned long long)bmsk) - 1);

  // single row pass: tile-skip scan + candidates + zero BOTH row halves
  const float Tc = T - 2.0f * DELTA;
  unsigned short* Brow = hrow(C, row);
  const uint4* Br4 = (const uint4*)Brow;
  uint4* Bw4 = (uint4*)Brow;                      // scratch half (16KB)
  float4* Zw4 = (float4*)(C + (size_t)row * NN);  // first 16KB = 1024 float4
  const float4 z4 = make_float4(0.f, 0.f, 0.f, 0.f);
  const uint4 zu4 = {0u, 0u, 0u, 0u};
  for (int it = 0; it < NN / 512; ++it) {
    // lane's 8 columns this iteration lie in tile it*4 + (lane>>4)
    const float tmx = __shfl(mv, it * 4 + (lane >> 4));
    const bool live = (tmx >= Tc);
    uint4 v = zu4;
    if (live) v = Br4[it * 64 + lane];
    Zw4[it * 64 + lane] = z4;
    Bw4[it * 64 + lane] = zu4;
    if (live) {
      int j = (it * 64 + lane) * 8;
      unsigned wv[4] = {v.x, v.y, v.z, v.w};
#pragma unroll
      for (int c = 0; c < 4; ++c) {
        float f0 = h2f((unsigned short)(wv[c] & 0xffffu));
        float f1 = h2f((unsigned short)(wv[c] >> 16));
        if (f0 >= Tc) { int p = atomicAdd(&wcnt[w], 1); if (p < CAPW) cidx[w][p] = j + 2 * c; }
        if (f1 >= Tc) { int p = atomicAdd(&wcnt[w], 1); if (p < CAPW) cidx[w][p] = j + 2 * c + 1; }
      }
    }
  }
  const int cnt = wcnt[w];
  const bool ok = (cnt <= CAPW);
  if (!ok && lane == 0) flags[row] = 1;

  // exact sequential-k fmaf chains (bit-identical to the verified chain)
  if (ok) {
    for (int c = lane; c < cnt; c += 64) {
      const float4* ej4 = (const float4*)(e32 + (size_t)cidx[w][c] * DD);
      float a = 0.f;
      for (int k4 = 0; k4 < DD / 4; ++k4) {
        float4 vv = ej4[k4];
        const float* e = &er[w][k4 * 4];
        a = fmaf(e[0], vv.x, a);
        a = fmaf(e[1], vv.y, a);
        a = fmaf(e[2], vv.z, a);
        a = fmaf(e[3], vv.w, a);
      }
      cval[w][c] = a;
    }

    // stable top-31 by (exact desc, idx asc) -> LDS kidx/kval
    for (int c = lane; c < cnt; c += 64) {
      float v = cval[w][c];
      int idx = cidx[w][c];
      int rnk = 0;
      for (int c2 = 0; c2 < cnt; ++c2) {
        float v2 = cval[w][c2];
        if (v2 > v || (v2 == v && cidx[w][c2] < idx)) ++rnk;
      }
      if (rnk < TOPK) {
        kidx[w][rnk] = idx;
        kval[w][rnk] = fmaxf(v, 0.0f);
      }
    }
  }

  // barrier drains all zero-stores (vmcnt 0) and publishes kidx/kval;
  // same-address ordering through L2 then serializes zero -> value.
  __syncthreads();

  if (ok && lane < TOPK) C[(size_t)row * NN + kidx[w][lane]] = kval[w][lane];
}

// ---------------------------------------------------------------------------
// Kernel D: exact cleanup for flagged rows (statistically never executes).
// ---------------------------------------------------------------------------
__global__ __launch_bounds__(256) void cleanup_kernel(
    float* __restrict__ C, const float* __restrict__ e32,
    const int* __restrict__ flags) {
  const int row = blockIdx.x;
  if (flags[row] == 0) return;
  const int tid = threadIdx.x;
  const int lane = tid & 63, wid = tid >> 6;

  __shared__ float sv[NN];
  __shared__ float er[DD];
  __shared__ unsigned long long wred[4];
  __shared__ int kidx[TOPK];
  __shared__ float kval[TOPK];

  {
    const float4* e4 = (const float4*)(e32 + (size_t)row * DD);
    if (tid < DD / 4) ((float4*)er)[tid] = e4[tid];
  }
  __syncthreads();

  for (int m = 0; m < NN / 256; ++m) {
    int j = m * 256 + tid;
    const float* ej = e32 + (size_t)j * DD;
    float a = 0.f;
    for (int k = 0; k < DD; k += 4) {
      float4 v = *(const float4*)&ej[k];
      a = fmaf(er[k], v.x, a);
      a = fmaf(er[k + 1], v.y, a);
      a = fmaf(er[k + 2], v.z, a);
      a = fmaf(er[k + 3], v.w, a);
    }
    sv[j] = a;
  }
  __syncthreads();

  for (int it = 0; it < TOPK; ++it) {
    float bv = -FLT_MAX;
    int bi = 0;
    for (int j = tid; j < NN; j += 256) {
      float v = sv[j];
      if (v > bv) { bv = v; bi = j; }
    }
    unsigned long long key =
        ((unsigned long long)ordmap(bv) << 32) | (unsigned)(NN - 1 - bi);
#pragma unroll
    for (int off = 32; off; off >>= 1) {
      unsigned long long o = __shfl_xor(key, off);
      if (o > key) key = o;
    }
    if (lane == 0) wred[wid] = key;
    __syncthreads();
    if (tid == 0) {
      unsigned long long k0 = wred[0];
      if (wred[1] > k0) k0 = wred[1];
      if (wred[2] > k0) k0 = wred[2];
      if (wred[3] > k0) k0 = wred[3];
      int idx = (NN - 1) - (int)(k0 & 0xFFFFFFFFu);
      kidx[it] = idx;
      kval[it] = sv[idx];
      sv[idx] = -FLT_MAX;
    }
    __syncthreads();
  }

  float4 z4 = make_float4(0.f, 0.f, 0.f, 0.f);
  float4* sv4 = (float4*)sv;
  for (int i = tid; i < NN / 4; i += 256) sv4[i] = z4;
  __syncthreads();
  if (tid < TOPK) sv[kidx[tid]] = fmaxf(kval[tid], 0.0f);
  __syncthreads();
  float4* Cw4 = (float4*)(C + (size_t)row * NN);
  for (int i = tid; i < NN / 4; i += 256) Cw4[i] = sv4[i];
}

// ---------------------------------------------------------------------------
extern "C" void kernel_launch(void* const* d_in, const int* in_sizes, int n_in,
                              void* d_out, int out_size, void* d_ws,
                              size_t ws_size, hipStream_t stream) {
  const float* f = (const float*)d_in[0];
  const float* W1 = (const float*)d_in[1];
  const float* W2 = (const float*)d_in[2];
  float* out = (float*)d_out;
  char* ws = (char*)d_ws;
  float* e32 = (float*)ws;                                     // 16 MiB
  _Float16* Ef = (_Float16*)(ws + (size_t)NN * DD * 4);        // 8 MiB
  float* TM = (float*)(ws + (size_t)NN * DD * 6);              // 2 MiB
  int* flags = (int*)(ws + (size_t)NN * DD * 6 + (size_t)NN * 64 * 4);  // 32 KB

  emb_kernel<<<NN / 4, 256, 0, stream>>>(f, W1, W2, e32, Ef, flags);
  sim_mfma<<<2080, 256, 0, stream>>>(Ef, out, TM);
  topk_collect<<<NN / 4, 256, 0, stream>>>(out, e32, TM, flags);
  cleanup_kernel<<<NN, 256, 0, stream>>>(out, e32, flags);
}